// Round 3
// baseline (2244.066 us; speedup 1.0000x reference)
//
#include <hip/hip_runtime.h>
#include <stdint.h>

// Problem constants (SimpleRNN reference)
#define VOCAB 50000
#define D     512
#define LSEQ  512
#define BATCH 256
#define NCLS  20

typedef unsigned short u16;
using f32x4 = __attribute__((ext_vector_type(4))) float;
using s16x8 = __attribute__((ext_vector_type(8))) short;
using u32x2 = __attribute__((ext_vector_type(2))) unsigned int;
using u32x4 = __attribute__((ext_vector_type(4))) unsigned int;

__device__ __forceinline__ float bf2f(u16 u){
  union { uint32_t i; float f; } v; v.i = ((uint32_t)u) << 16; return v.f;
}
__device__ __forceinline__ u16 f2bf(float f){
  uint32_t x = __float_as_uint(f);
  x += 0x7fffu + ((x >> 16) & 1u);          // RNE (values are tame, no NaN path)
  return (u16)(x >> 16);
}
__device__ __forceinline__ float bflo(uint32_t u){ return __uint_as_float(u << 16); }
__device__ __forceinline__ float bfhi(uint32_t u){ return __uint_as_float(u & 0xffff0000u); }
// tanh via v_exp_f32 + v_rcp_f32 (~5 VALU ops); saturates correctly at +/-inf.
__device__ __forceinline__ float fast_tanh(float x){
  float e = __builtin_amdgcn_exp2f(x * 2.8853900817779268f);   // e^(2x)
  return 1.0f - 2.0f * __builtin_amdgcn_rcpf(1.0f + e);
}

// ---------------------------------------------------------------------------
// Kernel 0: transpose + bf16-convert Wx and Wh -> Wxt/Wht [n][k] layout so
// MFMA A/B fragments (8 contiguous k per lane) are 16B vector loads.
// ---------------------------------------------------------------------------
__global__ void k_transpose_cvt(const float* __restrict__ Wx, const float* __restrict__ Wh,
                                u16* __restrict__ Wxt, u16* __restrict__ Wht){
  const int n = blockIdx.x & 511;
  const float* src = (blockIdx.x >> 9) ? Wh : Wx;
  u16* dst = (blockIdx.x >> 9) ? Wht : Wxt;
  for (int k = threadIdx.x; k < D; k += blockDim.x)
    dst[n * D + k] = f2bf(src[k * D + n]);   // strided read, coalesced write; ~1.5MB total
}

// ---------------------------------------------------------------------------
// Kernel 1: xin[l][b][:] = emb[x[b][l]] @ Wx + b   (stored bf16, [L][B][D])
// ---------------------------------------------------------------------------
__launch_bounds__(256, 2)
__global__ void k_xin(const int* __restrict__ x, const float* __restrict__ emb,
                      const u16* __restrict__ Wxt, const float* __restrict__ bias,
                      u16* __restrict__ xin){
  __shared__ __align__(16) u16 Bt_s[512 * 40];   // [n][32k + 8 pad] bf16, 40KB
  __shared__ int tok_s[64];
  const int tid  = threadIdx.x;
  const int lane = tid & 63, w = tid >> 6;
  const int nl   = lane & 15, q = lane >> 4;
  const int m0   = blockIdx.x * 64;

  if (tid < 64){
    int R = m0 + tid;                 // global row = l*256 + b
    int l = R >> 8, b = R & 255;
    tok_s[tid] = x[b * LSEQ + l];     // x is [B][L]
  }
  f32x4 acc[32];
  #pragma unroll
  for (int i = 0; i < 32; ++i) acc[i] = (f32x4)0.0f;
  __syncthreads();

  const int myrow = 16 * w + nl;                  // A-row m this lane feeds
  const float* arow = emb + (size_t)tok_s[myrow] * D;

  for (int kc = 0; kc < 16; ++kc){
    #pragma unroll
    for (int i = 0; i < 8; ++i){
      int idx = tid + 256 * i;
      int r = idx >> 2, cc = idx & 3;
      *(uint4*)&Bt_s[r * 40 + cc * 8] = *(const uint4*)(Wxt + r * D + kc * 32 + cc * 8);
    }
    __syncthreads();
    float4 f0 = *(const float4*)(arow + kc * 32 + q * 8);
    float4 f1 = *(const float4*)(arow + kc * 32 + q * 8 + 4);
    s16x8 a;
    a[0]=(short)f2bf(f0.x); a[1]=(short)f2bf(f0.y); a[2]=(short)f2bf(f0.z); a[3]=(short)f2bf(f0.w);
    a[4]=(short)f2bf(f1.x); a[5]=(short)f2bf(f1.y); a[6]=(short)f2bf(f1.z); a[7]=(short)f2bf(f1.w);
    #pragma unroll
    for (int nt = 0; nt < 32; ++nt){
      s16x8 b = *(const s16x8*)&Bt_s[(16 * nt + nl) * 40 + q * 8];
      acc[nt] = __builtin_amdgcn_mfma_f32_16x16x32_bf16(a, b, acc[nt], 0, 0, 0);
    }
    __syncthreads();
  }
  const int rowbase = m0 + 16 * w + 4 * q;
  #pragma unroll
  for (int nt = 0; nt < 32; ++nt){
    int col = 16 * nt + nl;
    float bc = bias[col];
    #pragma unroll
    for (int r = 0; r < 4; ++r)
      xin[(size_t)(rowbase + r) * D + col] = f2bf(acc[nt][r] + bc);
  }
}

// ---------------------------------------------------------------------------
// Kernel 2: recurrence, ZERO cross-block communication. 16 blocks x 512 thr
// (8 waves). Block g owns batch rows 16g..16g+15 AND all 512 columns: wave w
// holds Wh cols 64w..64w+63 as resident A-fragments (256 VGPRs). h lives in
// LDS (double-buffered, MFMA B-fragment layout): per step = ds_read frags ->
// 64 MFMA/wave -> +xin -> tanh -> ds_write -> one __syncthreads(). xin global
// loads issue at step start, consumed after MFMA loop (latency hidden).
// LDS frag layout: elem(k = kc*32+q*8+j, batch n) at [kc*512 + (q*16+n)*8 + j]
// -> reads are the canonical conflict-free b128 pattern; writes bank-uniform.
// ---------------------------------------------------------------------------
__launch_bounds__(512)
__global__ void k_rnn(const u16* __restrict__ xin, const u16* __restrict__ Wht,
                      float* __restrict__ hlast){
  __shared__ __align__(16) u16 h_s[2][16 * 512];   // 2 x 16KB
  const int tid  = threadIdx.x;
  const int lane = tid & 63, w = tid >> 6;         // 8 waves
  const int nl   = lane & 15, q = lane >> 4;
  const int g    = blockIdx.x;                     // batch rows 16g..16g+15
  const int colw = 64 * w;                         // this wave's 64 Wh-columns

  // Preload Wh A-fragments: A[m=nl][k] = Wh[k][colw+16mt+nl] = Wht[col][k]
  s16x8 whA[4][16];
  #pragma unroll
  for (int mt = 0; mt < 4; ++mt){
    const u16* wrow = Wht + (size_t)(colw + 16 * mt + nl) * D;
    #pragma unroll
    for (int kc = 0; kc < 16; ++kc)
      whA[mt][kc] = *(const s16x8*)(wrow + kc * 32 + q * 8);
  }

  // zero h(0) buffer (buf 1 is read at t=0)
  #pragma unroll
  for (int i = 0; i < 2; ++i)
    ((u32x4*)h_s[1])[tid + 512 * i] = (u32x4)0u;
  __syncthreads();

  // per-mt LDS write coords: col0 = colw + 16mt + 4q
  // kcw = 2w + (mt>>1); qd = (2mt + (q>>1)) & 3; j0 = (q&1)*4
  const int j0 = (q & 1) * 4;

  for (int t = 0; t < LSEQ; ++t){
    const int sw = t & 1, sr = sw ^ 1;

    // xin for this step (plain cached loads; waited only after MFMA loop)
    const u16* xp = xin + ((size_t)t * BATCH + g * 16 + nl) * D + colw + 4 * q;
    uint2 xv0 = *(const uint2*)(xp);
    uint2 xv1 = *(const uint2*)(xp + 16);
    uint2 xv2 = *(const uint2*)(xp + 32);
    uint2 xv3 = *(const uint2*)(xp + 48);

    f32x4 acc[4];
    #pragma unroll
    for (int mt = 0; mt < 4; ++mt) acc[mt] = (f32x4)0.0f;

    // K loop: B-frag shared across the 4 m-tiles
    #pragma unroll
    for (int kc = 0; kc < 16; ++kc){
      s16x8 hB = *(const s16x8*)&h_s[sr][kc * 512 + lane * 8];
      acc[0] = __builtin_amdgcn_mfma_f32_16x16x32_bf16(whA[0][kc], hB, acc[0], 0, 0, 0);
      acc[1] = __builtin_amdgcn_mfma_f32_16x16x32_bf16(whA[1][kc], hB, acc[1], 0, 0, 0);
      acc[2] = __builtin_amdgcn_mfma_f32_16x16x32_bf16(whA[2][kc], hB, acc[2], 0, 0, 0);
      acc[3] = __builtin_amdgcn_mfma_f32_16x16x32_bf16(whA[3][kc], hB, acc[3], 0, 0, 0);
    }

    // +xin, tanh, write h(t) to LDS in B-fragment layout
    const uint2 xv[4] = {xv0, xv1, xv2, xv3};
    #pragma unroll
    for (int mt = 0; mt < 4; ++mt){
      float v0 = fast_tanh(acc[mt][0] + bflo(xv[mt].x));
      float v1 = fast_tanh(acc[mt][1] + bfhi(xv[mt].x));
      float v2 = fast_tanh(acc[mt][2] + bflo(xv[mt].y));
      float v3 = fast_tanh(acc[mt][3] + bfhi(xv[mt].y));
      u32x2 pk;
      pk[0] = (uint32_t)f2bf(v0) | ((uint32_t)f2bf(v1) << 16);
      pk[1] = (uint32_t)f2bf(v2) | ((uint32_t)f2bf(v3) << 16);
      const int kcw = 2 * w + (mt >> 1);
      const int qd  = (2 * mt + (q >> 1)) & 3;
      *(u32x2*)&h_s[sw][kcw * 512 + (qd * 16 + nl) * 8 + j0] = pk;
      if (t == LSEQ - 1){
        float* hd = hlast + (size_t)(g * 16 + nl) * D + colw + 16 * mt + 4 * q;
        hd[0] = v0; hd[1] = v1; hd[2] = v2; hd[3] = v3;
      }
    }
    __syncthreads();   // h(t) visible to all waves; h(t-1) reads complete
  }
}

// ---------------------------------------------------------------------------
// Kernel 3: logits = h_last @ Wd + bd; softmax. One wave per batch row.
// ---------------------------------------------------------------------------
__global__ void k_head(const float* __restrict__ hlast, const float* __restrict__ Wd,
                       const float* __restrict__ bd, float* __restrict__ out){
  const int b = blockIdx.x;
  const int lane = threadIdx.x;          // 64 threads = 1 wave
  const float* hr = hlast + (size_t)b * D + lane * 8;
  float hv[8];
  #pragma unroll
  for (int i = 0; i < 8; ++i) hv[i] = hr[i];
  float acc[NCLS];
  #pragma unroll
  for (int c = 0; c < NCLS; ++c) acc[c] = 0.0f;
  #pragma unroll
  for (int i = 0; i < 8; ++i){
    const float* wr = Wd + (size_t)(lane * 8 + i) * NCLS;
    #pragma unroll
    for (int c = 0; c < NCLS; ++c) acc[c] += hv[i] * wr[c];
  }
  #pragma unroll
  for (int off = 32; off >= 1; off >>= 1){
    #pragma unroll
    for (int c = 0; c < NCLS; ++c) acc[c] += __shfl_xor(acc[c], off, 64);
  }
  float mx = -1e30f;
  #pragma unroll
  for (int c = 0; c < NCLS; ++c){ acc[c] += bd[c]; mx = fmaxf(mx, acc[c]); }
  float e[NCLS]; float s = 0.0f;
  #pragma unroll
  for (int c = 0; c < NCLS; ++c){
    e[c] = __builtin_amdgcn_exp2f((acc[c] - mx) * 1.4426950408889634f);
    s += e[c];
  }
  if (lane < NCLS) out[b * NCLS + lane] = e[lane] / s;
}

// ---------------------------------------------------------------------------
extern "C" void kernel_launch(void* const* d_in, const int* in_sizes, int n_in,
                              void* d_out, int out_size, void* d_ws, size_t ws_size,
                              hipStream_t stream){
  const int*   x    = (const int*)  d_in[0];
  const float* emb  = (const float*)d_in[1];
  const float* Wx   = (const float*)d_in[2];
  const float* Wh   = (const float*)d_in[3];
  const float* bias = (const float*)d_in[4];
  const float* Wd   = (const float*)d_in[5];
  const float* bd   = (const float*)d_in[6];
  float* out = (float*)d_out;
  char* ws = (char*)d_ws;

  const size_t XIN_B = (size_t)LSEQ * BATCH * D * 2;   // 134217728
  const size_t W_B   = (size_t)D * D * 2;              // 524288

  u16*   xin   = (u16*)  (ws);
  u16*   Wxt   = (u16*)  (ws + XIN_B);
  u16*   Wht   = (u16*)  (ws + XIN_B + W_B);
  float* hlast = (float*)(ws + XIN_B + 2 * W_B);       // fully written by k_rnn
  (void)in_sizes; (void)n_in; (void)out_size; (void)ws_size;

  k_transpose_cvt<<<dim3(1024), dim3(256), 0, stream>>>(Wx, Wh, Wxt, Wht);
  k_xin          <<<dim3(2048), dim3(256), 0, stream>>>(x, emb, Wxt, bias, xin);
  k_rnn          <<<dim3(16),   dim3(512), 0, stream>>>(xin, Wht, hlast);
  k_head         <<<dim3(256),  dim3(64),  0, stream>>>(hlast, Wd, bd, out);
}

// Round 4
// 1849.910 us; speedup vs baseline: 1.2131x; 1.2131x over previous
//
#include <hip/hip_runtime.h>
#include <stdint.h>

// Problem constants (SimpleRNN reference)
#define VOCAB 50000
#define D     512
#define LSEQ  512
#define BATCH 256
#define NCLS  20

typedef unsigned short u16;
typedef uint32_t u32;
using f32x4 = __attribute__((ext_vector_type(4))) float;
using s16x8 = __attribute__((ext_vector_type(8))) short;
using u32x2 = __attribute__((ext_vector_type(2))) unsigned int;
using u32x4 = __attribute__((ext_vector_type(4))) unsigned int;

__device__ __forceinline__ u16 f2bf(float f){
  uint32_t x = __float_as_uint(f);
  x += 0x7fffu + ((x >> 16) & 1u);          // RNE
  return (u16)(x >> 16);
}
__device__ __forceinline__ float bflo(uint32_t u){ return __uint_as_float(u << 16); }
__device__ __forceinline__ float bfhi(uint32_t u){ return __uint_as_float(u & 0xffff0000u); }
__device__ __forceinline__ float fast_tanh(float x){
  float e = __builtin_amdgcn_exp2f(x * 2.8853900817779268f);   // e^(2x)
  return 1.0f - 2.0f * __builtin_amdgcn_rcpf(1.0f + e);
}

// ---------------------------------------------------------------------------
// Kernel 0: transpose + bf16-convert Wx and Wh -> [n][k] layout.
// ---------------------------------------------------------------------------
__global__ void k_transpose_cvt(const float* __restrict__ Wx, const float* __restrict__ Wh,
                                u16* __restrict__ Wxt, u16* __restrict__ Wht){
  const int n = blockIdx.x & 511;
  const float* src = (blockIdx.x >> 9) ? Wh : Wx;
  u16* dst = (blockIdx.x >> 9) ? Wht : Wxt;
  for (int k = threadIdx.x; k < D; k += blockDim.x)
    dst[n * D + k] = f2bf(src[k * D + n]);
}

// ---------------------------------------------------------------------------
// Kernel 1: xin[l][b][:] = emb[x[b][l]] @ Wx + b   (stored bf16, [L][B][D])
// ---------------------------------------------------------------------------
__launch_bounds__(256, 2)
__global__ void k_xin(const int* __restrict__ x, const float* __restrict__ emb,
                      const u16* __restrict__ Wxt, const float* __restrict__ bias,
                      u16* __restrict__ xin){
  __shared__ __align__(16) u16 Bt_s[512 * 40];
  __shared__ int tok_s[64];
  const int tid  = threadIdx.x;
  const int lane = tid & 63, w = tid >> 6;
  const int nl   = lane & 15, q = lane >> 4;
  const int m0   = blockIdx.x * 64;

  if (tid < 64){
    int R = m0 + tid;
    int l = R >> 8, b = R & 255;
    tok_s[tid] = x[b * LSEQ + l];
  }
  f32x4 acc[32];
  #pragma unroll
  for (int i = 0; i < 32; ++i) acc[i] = (f32x4)0.0f;
  __syncthreads();

  const int myrow = 16 * w + nl;
  const float* arow = emb + (size_t)tok_s[myrow] * D;

  for (int kc = 0; kc < 16; ++kc){
    #pragma unroll
    for (int i = 0; i < 8; ++i){
      int idx = tid + 256 * i;
      int r = idx >> 2, cc = idx & 3;
      *(uint4*)&Bt_s[r * 40 + cc * 8] = *(const uint4*)(Wxt + r * D + kc * 32 + cc * 8);
    }
    __syncthreads();
    float4 f0 = *(const float4*)(arow + kc * 32 + q * 8);
    float4 f1 = *(const float4*)(arow + kc * 32 + q * 8 + 4);
    s16x8 a;
    a[0]=(short)f2bf(f0.x); a[1]=(short)f2bf(f0.y); a[2]=(short)f2bf(f0.z); a[3]=(short)f2bf(f0.w);
    a[4]=(short)f2bf(f1.x); a[5]=(short)f2bf(f1.y); a[6]=(short)f2bf(f1.z); a[7]=(short)f2bf(f1.w);
    #pragma unroll
    for (int nt = 0; nt < 32; ++nt){
      s16x8 b = *(const s16x8*)&Bt_s[(16 * nt + nl) * 40 + q * 8];
      acc[nt] = __builtin_amdgcn_mfma_f32_16x16x32_bf16(a, b, acc[nt], 0, 0, 0);
    }
    __syncthreads();
  }
  const int rowbase = m0 + 16 * w + 4 * q;
  #pragma unroll
  for (int nt = 0; nt < 32; ++nt){
    int col = 16 * nt + nl;
    float bc = bias[col];
    #pragma unroll
    for (int r = 0; r < 4; ++r)
      xin[(size_t)(rowbase + r) * D + col] = f2bf(acc[nt][r] + bc);
  }
}

// ---------------------------------------------------------------------------
// Kernel 2: recurrence. 64 blocks = 16 groups (16 batch rows) x 4 col-slices
// (128 cols; whA[2][16] resident, 4 waves). Exchange: h stored to LLC as u32
// (bf16<<16 | step_tag); consumers poll their own staged data for tag==t —
// poll IS the load, single LLC trip, no flags/fences/memset. Parity double-
// buffer makes overwrite logically impossible (producer reaching tag t+3
// implies all peers consumed tag t+1). Own slice goes straight to LDS.
// ---------------------------------------------------------------------------
__launch_bounds__(256, 1)
__global__ void k_rnn(const u16* __restrict__ xin, const u16* __restrict__ Wht,
                      u32* __restrict__ hx, float* __restrict__ hlast){
  __shared__ __align__(16) u16 h_s[2][16 * 512];   // B-frag layout, 2 x 16KB
  const int tid  = threadIdx.x;
  const int lane = tid & 63, w = tid >> 6;         // 4 waves
  const int nl   = lane & 15, q = lane >> 4;
  const int g    = blockIdx.x & 15;                // batch group
  const int j    = blockIdx.x >> 4;                // column-slice 0..3
  const int colbase = j * 128 + w * 32;
  const int grow    = g * 16;

  // resident Wh A-fragments: A[m=nl][k] = Wht[colbase+16mt+nl][k]
  s16x8 whA[2][16];
  #pragma unroll
  for (int mt = 0; mt < 2; ++mt){
    const u16* wrow = Wht + (size_t)(colbase + 16 * mt + nl) * D;
    #pragma unroll
    for (int kc = 0; kc < 16; ++kc)
      whA[mt][kc] = *(const s16x8*)(wrow + kc * 32 + q * 8);
  }

  // foreign-chunk coords: 3 slices x 512 dwordx4-chunks, 6 per lane
  int f_off[6], f_sidx[6];
  #pragma unroll
  for (int i = 0; i < 6; ++i){
    int s   = i >> 1;
    int idx = tid + 256 * (i & 1);
    int js  = (j + 1 + s) & 3;
    int r   = idx >> 5, cc = idx & 31;
    int col = js * 128 + cc * 4;
    f_off[i]  = (grow + r) * 512 + col;
    f_sidx[i] = (col >> 5) * 512 + (((col >> 3) & 3) * 16 + r) * 8 + (col & 7);
  }
  // own-slice coords per m-tile
  int cb[2], own_sidx[2], own_goff[2];
  #pragma unroll
  for (int mt = 0; mt < 2; ++mt){
    cb[mt]       = colbase + 16 * mt + 4 * q;
    own_sidx[mt] = (cb[mt] >> 5) * 512 + (((cb[mt] >> 3) & 3) * 16 + nl) * 8 + (cb[mt] & 7);
    own_goff[mt] = (grow + nl) * 512 + cb[mt];
  }

  for (int t = 0; t < LSEQ; ++t){
    const int pr = t & 1, p2 = pr ^ 1;
    u32x2 xa, xb;
    u32x4 c0, c1, c2, c3, c4, c5;
    const u16* xp = xin + ((size_t)t * BATCH + grow + nl) * D + colbase + 4 * q;

    if (t > 0){
      const u32 tt = (u32)t;
      const u32* pb = hx + (size_t)pr * 131072;
      // first issue: xin (cached) + 6 poll chunks (LLC), one waitcnt
      asm volatile(
        "global_load_dwordx2 %0, %8, off\n\t"
        "global_load_dwordx2 %1, %9, off\n\t"
        "global_load_dwordx4 %2, %10, off sc0 sc1\n\t"
        "global_load_dwordx4 %3, %11, off sc0 sc1\n\t"
        "global_load_dwordx4 %4, %12, off sc0 sc1\n\t"
        "global_load_dwordx4 %5, %13, off sc0 sc1\n\t"
        "global_load_dwordx4 %6, %14, off sc0 sc1\n\t"
        "global_load_dwordx4 %7, %15, off sc0 sc1\n\t"
        "s_waitcnt vmcnt(0)"
        : "=&v"(xa), "=&v"(xb), "=&v"(c0), "=&v"(c1), "=&v"(c2),
          "=&v"(c3), "=&v"(c4), "=&v"(c5)
        : "v"(xp), "v"(xp + 16), "v"(pb + f_off[0]), "v"(pb + f_off[1]),
          "v"(pb + f_off[2]), "v"(pb + f_off[3]), "v"(pb + f_off[4]), "v"(pb + f_off[5])
        : "memory");
      #define TAGBAD(cv) ((((cv)[0]^tt)|((cv)[1]^tt)|((cv)[2]^tt)|((cv)[3]^tt)) & 0xffffu)
      u32 bad = TAGBAD(c0) | TAGBAD(c1) | TAGBAD(c2) | TAGBAD(c3) | TAGBAD(c4) | TAGBAD(c5);
      while (__builtin_expect(bad != 0, 0)){
        asm volatile(
          "global_load_dwordx4 %0, %6, off sc0 sc1\n\t"
          "global_load_dwordx4 %1, %7, off sc0 sc1\n\t"
          "global_load_dwordx4 %2, %8, off sc0 sc1\n\t"
          "global_load_dwordx4 %3, %9, off sc0 sc1\n\t"
          "global_load_dwordx4 %4, %10, off sc0 sc1\n\t"
          "global_load_dwordx4 %5, %11, off sc0 sc1\n\t"
          "s_waitcnt vmcnt(0)"
          : "=&v"(c0), "=&v"(c1), "=&v"(c2), "=&v"(c3), "=&v"(c4), "=&v"(c5)
          : "v"(pb + f_off[0]), "v"(pb + f_off[1]), "v"(pb + f_off[2]),
            "v"(pb + f_off[3]), "v"(pb + f_off[4]), "v"(pb + f_off[5])
          : "memory");
        bad = TAGBAD(c0) | TAGBAD(c1) | TAGBAD(c2) | TAGBAD(c3) | TAGBAD(c4) | TAGBAD(c5);
      }
      #undef TAGBAD
      // stage foreign chunks -> LDS (bf16 = top16)
      const u32x4 cc6[6] = {c0, c1, c2, c3, c4, c5};
      #pragma unroll
      for (int i = 0; i < 6; ++i){
        u32x2 pk;
        pk[0] = (cc6[i][0] >> 16) | (cc6[i][1] & 0xffff0000u);
        pk[1] = (cc6[i][2] >> 16) | (cc6[i][3] & 0xffff0000u);
        *(u32x2*)&h_s[pr][f_sidx[i]] = pk;
      }
    } else {
      xa = *(const u32x2*)(xp);
      xb = *(const u32x2*)(xp + 16);
    }

    __syncthreads();    // staging + prev step's own-writes visible before frag reads

    f32x4 acc[2];
    acc[0] = (f32x4)0.0f; acc[1] = (f32x4)0.0f;
    if (t > 0){
      #pragma unroll
      for (int kc = 0; kc < 16; ++kc){
        s16x8 hB = *(const s16x8*)&h_s[pr][kc * 512 + lane * 8];
        acc[0] = __builtin_amdgcn_mfma_f32_16x16x32_bf16(whA[0][kc], hB, acc[0], 0, 0, 0);
        acc[1] = __builtin_amdgcn_mfma_f32_16x16x32_bf16(whA[1][kc], hB, acc[1], 0, 0, 0);
      }
    }

    // h(t+1) = tanh(xin + acc)
    const u32x2 xv[2] = {xa, xb};
    const u32 tag = (u32)(t + 1);
    #pragma unroll
    for (int mt = 0; mt < 2; ++mt){
      float v0 = fast_tanh(acc[mt][0] + bflo(xv[mt][0]));
      float v1 = fast_tanh(acc[mt][1] + bfhi(xv[mt][0]));
      float v2 = fast_tanh(acc[mt][2] + bflo(xv[mt][1]));
      float v3 = fast_tanh(acc[mt][3] + bfhi(xv[mt][1]));
      if (t < LSEQ - 1){
        u16 b0 = f2bf(v0), b1 = f2bf(v1), b2 = f2bf(v2), b3 = f2bf(v3);
        u32x2 pk; pk[0] = (u32)b0 | ((u32)b1 << 16); pk[1] = (u32)b2 | ((u32)b3 << 16);
        *(u32x2*)&h_s[p2][own_sidx[mt]] = pk;     // own slice direct to LDS
        u32x4 st;
        st[0] = ((u32)b0 << 16) | tag; st[1] = ((u32)b1 << 16) | tag;
        st[2] = ((u32)b2 << 16) | tag; st[3] = ((u32)b3 << 16) | tag;
        asm volatile("global_store_dwordx4 %0, %1, off sc0 sc1"
                     :: "v"(hx + (size_t)p2 * 131072 + own_goff[mt]), "v"(st) : "memory");
      } else {
        float* hd = hlast + (size_t)(grow + nl) * D + cb[mt];
        hd[0] = v0; hd[1] = v1; hd[2] = v2; hd[3] = v3;
      }
    }
    // no end barrier needed: next-step staging targets the other LDS buffer,
    // and own-writes to a buffer only happen after ALL waves passed the top
    // barrier that follows every wave's reads of that buffer.
  }
}

// ---------------------------------------------------------------------------
// Kernel 3: logits = h_last @ Wd + bd; softmax. One wave per batch row.
// ---------------------------------------------------------------------------
__global__ void k_head(const float* __restrict__ hlast, const float* __restrict__ Wd,
                       const float* __restrict__ bd, float* __restrict__ out){
  const int b = blockIdx.x;
  const int lane = threadIdx.x;
  const float* hr = hlast + (size_t)b * D + lane * 8;
  float hv[8];
  #pragma unroll
  for (int i = 0; i < 8; ++i) hv[i] = hr[i];
  float acc[NCLS];
  #pragma unroll
  for (int c = 0; c < NCLS; ++c) acc[c] = 0.0f;
  #pragma unroll
  for (int i = 0; i < 8; ++i){
    const float* wr = Wd + (size_t)(lane * 8 + i) * NCLS;
    #pragma unroll
    for (int c = 0; c < NCLS; ++c) acc[c] += hv[i] * wr[c];
  }
  #pragma unroll
  for (int off = 32; off >= 1; off >>= 1){
    #pragma unroll
    for (int c = 0; c < NCLS; ++c) acc[c] += __shfl_xor(acc[c], off, 64);
  }
  float mx = -1e30f;
  #pragma unroll
  for (int c = 0; c < NCLS; ++c){ acc[c] += bd[c]; mx = fmaxf(mx, acc[c]); }
  float e[NCLS]; float s = 0.0f;
  #pragma unroll
  for (int c = 0; c < NCLS; ++c){
    e[c] = __builtin_amdgcn_exp2f((acc[c] - mx) * 1.4426950408889634f);
    s += e[c];
  }
  if (lane < NCLS) out[b * NCLS + lane] = e[lane] / s;
}

// ---------------------------------------------------------------------------
extern "C" void kernel_launch(void* const* d_in, const int* in_sizes, int n_in,
                              void* d_out, int out_size, void* d_ws, size_t ws_size,
                              hipStream_t stream){
  const int*   x    = (const int*)  d_in[0];
  const float* emb  = (const float*)d_in[1];
  const float* Wx   = (const float*)d_in[2];
  const float* Wh   = (const float*)d_in[3];
  const float* bias = (const float*)d_in[4];
  const float* Wd   = (const float*)d_in[5];
  const float* bd   = (const float*)d_in[6];
  float* out = (float*)d_out;
  char* ws = (char*)d_ws;

  const size_t XIN_B = (size_t)LSEQ * BATCH * D * 2;   // 134217728
  const size_t W_B   = (size_t)D * D * 2;              // 524288
  const size_t HX_B  = (size_t)2 * BATCH * D * 4;      // 1048576 (tagged u32 h)

  u16*   xin   = (u16*)  (ws);
  u16*   Wxt   = (u16*)  (ws + XIN_B);
  u16*   Wht   = (u16*)  (ws + XIN_B + W_B);
  u32*   hx    = (u32*)  (ws + XIN_B + 2 * W_B);
  float* hlast = (float*)(ws + XIN_B + 2 * W_B + HX_B);
  (void)in_sizes; (void)n_in; (void)out_size; (void)ws_size;

  // no memset needed: tag protocol distinguishes fresh data from 0xAA poison,
  // h(0)=0 is realized by skipping the K-loop at t=0.
  k_transpose_cvt<<<dim3(1024), dim3(256), 0, stream>>>(Wx, Wh, Wxt, Wht);
  k_xin          <<<dim3(2048), dim3(256), 0, stream>>>(x, emb, Wxt, bias, xin);
  k_rnn          <<<dim3(64),   dim3(256), 0, stream>>>(xin, Wht, hx, hlast);
  k_head         <<<dim3(256),  dim3(64),  0, stream>>>(hlast, Wd, bd, out);
}